// Round 1
// baseline (130.317 us; speedup 1.0000x reference)
//
#include <hip/hip_runtime.h>

constexpr int NC = 32;    // channels C
constexpr int NH = 8;     // heads
constexpr int NS = 128;   // s
constexpr int NI = 256;   // i (q rows)
constexpr int NJ = 256;   // j (kv rows)
constexpr float LN_EPS = 1e-5f;
constexpr float QSCALE = 0.17677669529663687f;   // C^-0.5
constexpr float LOG2E  = 1.4426950408889634f;

typedef __bf16 bf16x8 __attribute__((ext_vector_type(8)));
typedef __bf16 bf16x2 __attribute__((ext_vector_type(2)));
typedef float floatx4 __attribute__((ext_vector_type(4)));

__device__ __forceinline__ float fexp2(float x) {
#if __has_builtin(__builtin_amdgcn_exp2f)
    return __builtin_amdgcn_exp2f(x);
#else
    return exp2f(x);
#endif
}
__device__ __forceinline__ float frcp(float x) {
#if __has_builtin(__builtin_amdgcn_rcpf)
    return __builtin_amdgcn_rcpf(x);
#else
    return 1.0f / x;
#endif
}
// HW bf16 pack (v_cvt_pk_bf16_f32 on gfx950), RNE
__device__ __forceinline__ unsigned pk2c(float a, float b) {
    union { bf16x2 v; unsigned u; } c;
    c.v = bf16x2{(__bf16)a, (__bf16)b};
    return c.u;
}
__device__ __forceinline__ unsigned pkbb(__bf16 a, __bf16 b) {
    union { bf16x2 v; unsigned u; } c;
    c.v = bf16x2{a, b};
    return c.u;
}
// fp32 atomic add, HW global_atomic_add_f32 (no CAS loop, no return)
__device__ __forceinline__ void atomAddF32(float* p, float v) {
    unsafeAtomicAdd(p, v);
}

// XOR-swizzled LDS offsets (shorts). Rows of 32 shorts (4 x 16B chunks):
// phys_chunk = chunk ^ ((row>>1)&3)  -> <=2-way banks on all b128 reads.
__device__ __forceinline__ int qkOff(int row, int chunk) {
    return row * 32 + ((chunk ^ ((row >> 1) & 3)) << 3);
}
// V^T rows of 256 shorts (32 chunks): phys_chunk = chunk ^ (c&7).
__device__ __forceinline__ int vOff(int c, int chunk) {
    return c * 256 + ((chunk ^ (c & 7)) << 3);
}

// ---------------------------------------------------------------------------
// Kernel 1 (merged): blocks 0..255   : pair bias -> fp32 MFMA-C-fragment layout
//                    blocks 256..271 : wq/wk/wv/wg fragment prep (bf16)
//                    blocks 272..275 : wo B-fragment prep (bf16)
// All blocks: tail grid-stride loop initializes out = bo (attn_kernel
// atomically accumulates the per-head projection partials into it).
// bias32 layout: off(h,i,j) = h*65536 + jc*8192 + w*2048 + (jt*4+it)*256 + l*4 + r
//   log2e folded in (exp2 path).
// ---------------------------------------------------------------------------
__global__ __launch_bounds__(256) void biasprep_kernel(
    const float* __restrict__ z, const float* __restrict__ lnb_s,
    const float* __restrict__ lnb_b, const float* __restrict__ wb,
    const float* __restrict__ wq, const float* __restrict__ wk,
    const float* __restrict__ wv, const float* __restrict__ wg,
    const float* __restrict__ wo, const float* __restrict__ bo,
    float* __restrict__ bias32, unsigned short* __restrict__ wprep,
    unsigned short* __restrict__ wofrag, float* __restrict__ out)
{
    const int b = blockIdx.x;
    const int t = threadIdx.x;
    if (b < 256) {
        // ---- bias: block = one i, threads = j. Coalesced z stage via LDS. ----
        __shared__ float zL[256 * 33];               // pitch 33: conflict-free rows
        const float4* src = (const float4*)(z + (size_t)b * NJ * NC);
#pragma unroll
        for (int k = 0; k < 8; ++k) {
            int idx = t + 256 * k;                   // float4 index
            float4 v = src[idx];
            int f = idx * 4;
            int j = f >> 5, c = f & 31;
            zL[j * 33 + c]     = v.x; zL[j * 33 + c + 1] = v.y;
            zL[j * 33 + c + 2] = v.z; zL[j * 33 + c + 3] = v.w;
        }
        __syncthreads();

        float x[NC];
#pragma unroll
        for (int c = 0; c < NC; ++c) x[c] = zL[t * 33 + c];
        float mu = 0.f;
#pragma unroll
        for (int c = 0; c < NC; ++c) mu += x[c];
        mu *= (1.0f / NC);
        float var = 0.f;
#pragma unroll
        for (int c = 0; c < NC; ++c) { float d = x[c] - mu; var += d * d; }
        var *= (1.0f / NC);
        float rs = rsqrtf(var + LN_EPS);
        float acc[NH];
#pragma unroll
        for (int h = 0; h < NH; ++h) acc[h] = 0.f;
#pragma unroll
        for (int c = 0; c < NC; ++c) {
            float xn = (x[c] - mu) * rs * lnb_s[c] + lnb_b[c];
#pragma unroll
            for (int h = 0; h < NH; ++h) acc[h] += xn * wb[c * NH + h];
        }
        const int i = b;
        const int w_ = i >> 6, it = (i >> 4) & 3, lm = i & 15;
        const int jc = t >> 5, jt = (t >> 4) & 1, lq = (t >> 2) & 3, r = t & 3;
        const int base = jc * 8192 + w_ * 2048 + (jt * 4 + it) * 256
                       + (lq * 16 + lm) * 4 + r;
#pragma unroll
        for (int h = 0; h < NH; ++h)
            bias32[h * 65536 + base] = acc[h] * LOG2E;
    } else if (b < 272) {
        // ---- QKVG weight fragments ----
        int g = (b - 256) * 256 + t;                 // 0..4095
        int p  = g >> 10;
        int h  = (g >> 7) & 7;
        int ct = (g >> 6) & 1;
        int l  = g & 63;
        const float* W = (p == 0) ? wq : (p == 1) ? wk : (p == 2) ? wv : wg;
        float scale = (p == 0) ? QSCALE * LOG2E : (p == 3) ? LOG2E : 1.0f;
        int col = 32 * h + 16 * ct + (l & 15);
        int r0  = 8 * (l >> 4);
        float v[8];
#pragma unroll
        for (int e = 0; e < 8; ++e) v[e] = W[(r0 + e) * 256 + col] * scale;
        uint4 u;
        u.x = pk2c(v[0], v[1]); u.y = pk2c(v[2], v[3]);
        u.z = pk2c(v[4], v[5]); u.w = pk2c(v[6], v[7]);
        *(uint4*)&wprep[g * 8] = u;
    } else {
        // ---- wo B-fragments ----
        int g = (b - 272) * 256 + t;                 // 0..1023
        int tile = g >> 6;                           // kt*2+nt
        int l = g & 63;
        int kt = tile >> 1, nt = tile & 1;
        int r0 = kt * 32 + 8 * (l >> 4);
        int col = nt * 16 + (l & 15);
        float v[8];
#pragma unroll
        for (int e = 0; e < 8; ++e) v[e] = wo[(r0 + e) * 32 + col];
        uint4 u;
        u.x = pk2c(v[0], v[1]); u.y = pk2c(v[2], v[3]);
        u.z = pk2c(v[4], v[5]); u.w = pk2c(v[6], v[7]);
        *(uint4*)&wofrag[g * 8] = u;
    }

    // ---- out = bo  (float4 grid-stride; attn_kernel atomically adds) ----
    {
        const int gtid = b * 256 + t;
        constexpr int NF4 = NS * NI * NC / 4;        // 262144
        for (int idx = gtid; idx < NF4; idx += 276 * 256) {
            int c4 = (idx & 7) * 4;
            float4 v = {bo[c4], bo[c4 + 1], bo[c4 + 2], bo[c4 + 3]};
            ((float4*)out)[idx] = v;
        }
    }
}

// ---------------------------------------------------------------------------
// Kernel 2: all-MFMA fused attention + fused output projection.
// 48 KB LDS -> 3 blocks/CU (12 waves). XOR-swizzled LDS (no padding).
// Denominator via ones-MFMA. Single P buffer. Per-jt processing keeps
// loop-live VGPRs ~<160.
// Epilogue: gate+normalize -> pack o (bf16) into wave-private QPX rows ->
// read A-frags -> 8 MFMAs vs wofrag (K-chunk = h) -> fp32 atomicAdd into out.
// Removes the 33.5 MB attn16 round-trip and the proj_kernel launch.
// LDS: QPX (X -> Q^T -> P -> o) 16K | Kt 16K | Vt 16K = 48 KB.
// ---------------------------------------------------------------------------
__global__ __launch_bounds__(256, 3) void attn_kernel(
    const float* __restrict__ m, const float* __restrict__ ln_s,
    const float* __restrict__ ln_b,
    const unsigned short* __restrict__ wprep,
    const float* __restrict__ bias32,
    const unsigned short* __restrict__ wofrag,
    float* __restrict__ out)
{
    __shared__ unsigned short QPX[256 * 32];     // X -> Q^T -> P -> o rows
    __shared__ unsigned short Kt[256 * 32];      // K rows [j][c]
    __shared__ unsigned short Vt[32 * 256];      // V^T [c][j]

    const int t = threadIdx.x;
    const int h = blockIdx.x & 7;
    const int s = blockIdx.x >> 3;
    const int l = t & 63, w = t >> 6;
    const int lm = l & 15, lq = l >> 4;
    const int ibase = w * 64;
    const floatx4 zero = {0.f, 0.f, 0.f, 0.f};

    // ---- Phase 1: LN(m[s][t]) -> QPX row t (bf16, swizzled). Wave-private. ----
    {
        const float4* mr = (const float4*)(m + ((size_t)s * NI + t) * NC);
        float x[NC];
#pragma unroll
        for (int k = 0; k < 8; ++k) {
            float4 v = mr[k];
            x[4*k] = v.x; x[4*k+1] = v.y; x[4*k+2] = v.z; x[4*k+3] = v.w;
        }
        float mu = 0.f;
#pragma unroll
        for (int c = 0; c < NC; ++c) mu += x[c];
        mu *= (1.0f / NC);
        float var = 0.f;
#pragma unroll
        for (int c = 0; c < NC; ++c) { float d = x[c] - mu; var += d * d; }
        var *= (1.0f / NC);
        float rs = rsqrtf(var + LN_EPS);
#pragma unroll
        for (int k = 0; k < 4; ++k) {
            uint4 u;
            u.x = pk2c((x[8*k+0]-mu)*rs*ln_s[8*k+0]+ln_b[8*k+0],
                       (x[8*k+1]-mu)*rs*ln_s[8*k+1]+ln_b[8*k+1]);
            u.y = pk2c((x[8*k+2]-mu)*rs*ln_s[8*k+2]+ln_b[8*k+2],
                       (x[8*k+3]-mu)*rs*ln_s[8*k+3]+ln_b[8*k+3]);
            u.z = pk2c((x[8*k+4]-mu)*rs*ln_s[8*k+4]+ln_b[8*k+4],
                       (x[8*k+5]-mu)*rs*ln_s[8*k+5]+ln_b[8*k+5]);
            u.w = pk2c((x[8*k+6]-mu)*rs*ln_s[8*k+6]+ln_b[8*k+6],
                       (x[8*k+7]-mu)*rs*ln_s[8*k+7]+ln_b[8*k+7]);
            *(uint4*)&QPX[qkOff(t, k)] = u;
        }
    }
    // no barrier: wave-private rows

    // ---- Phase 2: MFMA projections (Q/K/V). Gate deferred to epilogue. ----
    const unsigned short* wp = wprep + ((size_t)h * 128 + l) * 8;
    bf16x8 wfQ[2], wfK[2], wfV[2];
#pragma unroll
    for (int ct = 0; ct < 2; ++ct) {
        wfQ[ct] = *(const bf16x8*)&wp[(0 * 1024 + ct * 64) * 8];
        wfK[ct] = *(const bf16x8*)&wp[(1 * 1024 + ct * 64) * 8];
        wfV[ct] = *(const bf16x8*)&wp[(2 * 1024 + ct * 64) * 8];
    }
    bf16x8 Xb[4];                                 // retained for epilogue gate
#pragma unroll
    for (int it = 0; it < 4; ++it)
        Xb[it] = *(const bf16x8*)&QPX[qkOff(ibase + it * 16 + lm, lq)];
    // QPX (X) now dead for this wave -> reuse for Q^T

    // Q^T rows [i][c]  (D[c][i]: lane lm = i, regs = 4 consecutive c)
#pragma unroll
    for (int it = 0; it < 4; ++it)
#pragma unroll
        for (int ct = 0; ct < 2; ++ct) {
            floatx4 d = __builtin_amdgcn_mfma_f32_16x16x32_bf16(wfQ[ct], Xb[it], zero, 0, 0, 0);
            uint2 u; u.x = pk2c(d[0], d[1]); u.y = pk2c(d[2], d[3]);
            int row = ibase + it * 16 + lm;
            *(uint2*)&QPX[qkOff(row, 2 * ct + (lq >> 1)) + (lq & 1) * 4] = u;
        }
    // K^T rows [j][c]
#pragma unroll
    for (int it = 0; it < 4; ++it)
#pragma unroll
        for (int ct = 0; ct < 2; ++ct) {
            floatx4 d = __builtin_amdgcn_mfma_f32_16x16x32_bf16(wfK[ct], Xb[it], zero, 0, 0, 0);
            uint2 u; u.x = pk2c(d[0], d[1]); u.y = pk2c(d[2], d[3]);
            int row = ibase + it * 16 + lm;
            *(uint2*)&Kt[qkOff(row, 2 * ct + (lq >> 1)) + (lq & 1) * 4] = u;
        }
    // V -> Vt [c][j]  (D[j][c']: lane lm = c', regs = 4 consecutive j)
#pragma unroll
    for (int jt = 0; jt < 4; ++jt)
#pragma unroll
        for (int ct = 0; ct < 2; ++ct) {
            floatx4 d = __builtin_amdgcn_mfma_f32_16x16x32_bf16(Xb[jt], wfV[ct], zero, 0, 0, 0);
            uint2 u; u.x = pk2c(d[0], d[1]); u.y = pk2c(d[2], d[3]);
            int c = ct * 16 + lm;
            int chunk = 8 * w + 2 * jt + (lq >> 1);
            *(uint2*)&Vt[vOff(c, chunk) + (lq & 1) * 4] = u;
        }

    // Hoist own Q^T B-frags before the barrier (wave-private rows)
    bf16x8 Qb[4];
#pragma unroll
    for (int it = 0; it < 4; ++it)
        Qb[it] = *(const bf16x8*)&QPX[qkOff(ibase + it * 16 + lm, lq)];

    __syncthreads();   // Kt / Vt visible to all waves (the only barrier)

    floatx4 accO[2][4];
#pragma unroll
    for (int ct = 0; ct < 2; ++ct)
#pragma unroll
        for (int it = 0; it < 4; ++it) accO[ct][it] = zero;
    floatx4 accL[4];                // denominator via ones-MFMA
#pragma unroll
    for (int it = 0; it < 4; ++it) accL[it] = zero;
    bf16x8 ones;
#pragma unroll
    for (int e = 0; e < 8; ++e) ones[e] = (__bf16)1.0f;

    const float* bptr = bias32 + (size_t)h * 65536 + w * 2048 + l * 4;

    // ---- Phase 3: j-loop, 32 j per iteration ----
    for (int jc = 0; jc < 8; ++jc) {
        const int j0 = jc * 32;
        const float* bj = bptr + jc * 8192;

        // S = K x Q^T + bias(C);  p = exp2(S); pack P rows (per-jt: low liveness)
#pragma unroll
        for (int jt = 0; jt < 2; ++jt) {
            bf16x8 Ka = *(const bf16x8*)&Kt[qkOff(j0 + jt * 16 + lm, lq)];
#pragma unroll
            for (int it = 0; it < 4; ++it) {
                floatx4 C = *(const floatx4*)(bj + (jt * 4 + it) * 256);
                floatx4 S = __builtin_amdgcn_mfma_f32_16x16x32_bf16(Ka, Qb[it], C, 0, 0, 0);
                __bf16 p0 = (__bf16)fexp2(S[0]);
                __bf16 p1 = (__bf16)fexp2(S[1]);
                __bf16 p2 = (__bf16)fexp2(S[2]);
                __bf16 p3 = (__bf16)fexp2(S[3]);
                uint2 u; u.x = pkbb(p0, p1); u.y = pkbb(p2, p3);
                int row = ibase + it * 16 + lm;
                *(uint2*)&QPX[qkOff(row, 2 * jt + (lq >> 1)) + (lq & 1) * 4] = u;
            }
        }

        // PV + denominator: O^T[c][i] += V^T x P^T ; L[i] += ones x P^T
        bf16x8 Va0 = *(const bf16x8*)&Vt[vOff(lm, 4 * jc + lq)];
        bf16x8 Va1 = *(const bf16x8*)&Vt[vOff(16 + lm, 4 * jc + lq)];
#pragma unroll
        for (int it = 0; it < 4; ++it) {
            bf16x8 Pb = *(const bf16x8*)&QPX[qkOff(ibase + it * 16 + lm, lq)];
            accO[0][it] = __builtin_amdgcn_mfma_f32_16x16x32_bf16(Va0, Pb, accO[0][it], 0, 0, 0);
            accO[1][it] = __builtin_amdgcn_mfma_f32_16x16x32_bf16(Va1, Pb, accO[1][it], 0, 0, 0);
            accL[it]    = __builtin_amdgcn_mfma_f32_16x16x32_bf16(ones, Pb, accL[it], 0, 0, 0);
        }
    }

    // ---- Epilogue: gate from retained Xb, normalize, pack o into QPX ----
    {
        bf16x8 wfG0 = *(const bf16x8*)&wp[(3 * 1024 + 0 * 64) * 8];
        bf16x8 wfG1 = *(const bf16x8*)&wp[(3 * 1024 + 1 * 64) * 8];
#pragma unroll
        for (int it = 0; it < 4; ++it) {
            floatx4 d0 = __builtin_amdgcn_mfma_f32_16x16x32_bf16(wfG0, Xb[it], zero, 0, 0, 0);
            floatx4 d1 = __builtin_amdgcn_mfma_f32_16x16x32_bf16(wfG1, Xb[it], zero, 0, 0, 0);
            const float inv = frcp(accL[it][0]);     // all lanes/regs hold own i's L
            const int row = ibase + it * 16 + lm;
            {   // ct = 0: c = lq*4 + r
                float o0 = accO[0][it][0] * inv * frcp(1.0f + fexp2(-d0[0]));
                float o1 = accO[0][it][1] * inv * frcp(1.0f + fexp2(-d0[1]));
                float o2 = accO[0][it][2] * inv * frcp(1.0f + fexp2(-d0[2]));
                float o3 = accO[0][it][3] * inv * frcp(1.0f + fexp2(-d0[3]));
                uint2 u; u.x = pk2c(o0, o1); u.y = pk2c(o2, o3);
                *(uint2*)&QPX[qkOff(row, 0 + (lq >> 1)) + (lq & 1) * 4] = u;
            }
            {   // ct = 1: c = 16 + lq*4 + r
                float o0 = accO[1][it][0] * inv * frcp(1.0f + fexp2(-d1[0]));
                float o1 = accO[1][it][1] * inv * frcp(1.0f + fexp2(-d1[1]));
                float o2 = accO[1][it][2] * inv * frcp(1.0f + fexp2(-d1[2]));
                float o3 = accO[1][it][3] * inv * frcp(1.0f + fexp2(-d1[3]));
                uint2 u; u.x = pk2c(o0, o1); u.y = pk2c(o2, o3);
                *(uint2*)&QPX[qkOff(row, 2 + (lq >> 1)) + (lq & 1) * 4] = u;
            }
        }
    }

    // ---- Fused output projection: out[i][:] += o_h(i, 0:32) @ wo_h ----
    // A-frag: QPX row i (lane lm = i, k-chunk lq -> 8 consecutive c).
    // B-frag: wofrag tile (h*2 + nt), prepped exactly for K-chunk kt = h.
    // D[i][n]: col n = lm, row i = it*16 + lq*4 + r. No barrier needed
    // (wave-private QPX rows); atomics are fire-and-forget fp32 HW adds.
    {
        bf16x8 wob0 = *(const bf16x8*)&wofrag[((size_t)(h * 2 + 0) * 64 + l) * 8];
        bf16x8 wob1 = *(const bf16x8*)&wofrag[((size_t)(h * 2 + 1) * 64 + l) * 8];
#pragma unroll
        for (int it = 0; it < 4; ++it) {
            bf16x8 of = *(const bf16x8*)&QPX[qkOff(ibase + it * 16 + lm, lq)];
            floatx4 p0 = __builtin_amdgcn_mfma_f32_16x16x32_bf16(of, wob0, zero, 0, 0, 0);
            floatx4 p1 = __builtin_amdgcn_mfma_f32_16x16x32_bf16(of, wob1, zero, 0, 0, 0);
            float* orow = out + ((size_t)s * NI + ibase + it * 16 + lq * 4) * NC;
#pragma unroll
            for (int r = 0; r < 4; ++r) {
                atomAddF32(orow + r * NC + lm,      p0[r]);
                atomAddF32(orow + r * NC + 16 + lm, p1[r]);
            }
        }
    }
}

// ---------------------------------------------------------------------------
extern "C" void kernel_launch(void* const* d_in, const int* in_sizes, int n_in,
                              void* d_out, int out_size, void* d_ws, size_t ws_size,
                              hipStream_t stream) {
    const float* m     = (const float*)d_in[0];
    const float* z     = (const float*)d_in[1];
    const float* ln_s  = (const float*)d_in[2];
    const float* ln_b  = (const float*)d_in[3];
    const float* lnb_s = (const float*)d_in[4];
    const float* lnb_b = (const float*)d_in[5];
    const float* wq    = (const float*)d_in[6];
    const float* wk    = (const float*)d_in[7];
    const float* wv    = (const float*)d_in[8];
    const float* wb    = (const float*)d_in[9];
    const float* wg    = (const float*)d_in[10];
    const float* wo    = (const float*)d_in[11];
    const float* bo    = (const float*)d_in[12];
    float* out = (float*)d_out;

    // ws: bias32 2 MB | wprep 64 KB | wofrag 16 KB
    float* bias32 = (float*)d_ws;
    unsigned short* wprep  = (unsigned short*)((char*)d_ws + (2u << 20));
    unsigned short* wofrag = (unsigned short*)((char*)d_ws + (2u << 20) + 65536);

    biasprep_kernel<<<276, 256, 0, stream>>>(z, lnb_s, lnb_b, wb, wq, wk, wv, wg,
                                             wo, bo, bias32, wprep, wofrag, out);
    attn_kernel<<<NS * NH, 256, 0, stream>>>(m, ln_s, ln_b, wprep, bias32,
                                             wofrag, out);
}

// Round 2
// 128.251 us; speedup vs baseline: 1.0161x; 1.0161x over previous
//
#include <hip/hip_runtime.h>

constexpr int NC = 32;    // channels C
constexpr int NH = 8;     // heads
constexpr int NS = 128;   // s
constexpr int NI = 256;   // i (q rows)
constexpr int NJ = 256;   // j (kv rows)
constexpr float LN_EPS = 1e-5f;
constexpr float QSCALE = 0.17677669529663687f;   // C^-0.5
constexpr float LOG2E  = 1.4426950408889634f;

typedef __bf16 bf16x8 __attribute__((ext_vector_type(8)));
typedef __bf16 bf16x2 __attribute__((ext_vector_type(2)));
typedef float floatx4 __attribute__((ext_vector_type(4)));
typedef short short4v __attribute__((ext_vector_type(4)));

__device__ __forceinline__ float fexp2(float x) {
#if __has_builtin(__builtin_amdgcn_exp2f)
    return __builtin_amdgcn_exp2f(x);
#else
    return exp2f(x);
#endif
}
__device__ __forceinline__ float frcp(float x) {
#if __has_builtin(__builtin_amdgcn_rcpf)
    return __builtin_amdgcn_rcpf(x);
#else
    return 1.0f / x;
#endif
}
// HW bf16 pack (v_cvt_pk_bf16_f32 on gfx950), RNE
__device__ __forceinline__ unsigned pk2c(float a, float b) {
    union { bf16x2 v; unsigned u; } c;
    c.v = bf16x2{(__bf16)a, (__bf16)b};
    return c.u;
}
__device__ __forceinline__ unsigned pkbb(__bf16 a, __bf16 b) {
    union { bf16x2 v; unsigned u; } c;
    c.v = bf16x2{a, b};
    return c.u;
}

// XOR-swizzled LDS offsets (shorts). Rows of 32 shorts (4 x 16B chunks):
// phys_chunk = chunk ^ ((row>>1)&3)  -> <=2-way banks on all b128 reads.
__device__ __forceinline__ int qkOff(int row, int chunk) {
    return row * 32 + ((chunk ^ ((row >> 1) & 3)) << 3);
}

// ---------------------------------------------------------------------------
// Kernel 1 (merged): blocks 0..255   : pair bias -> fp32 MFMA-C-fragment layout
//                    blocks 256..271 : wq/wk/wv/wg fragment prep (bf16)
//                    blocks 272..275 : wo B-fragment prep (bf16)
// bias32 layout: off(h,i,j) = h*65536 + jc*8192 + w*2048 + (jt*4+it)*256 + l*4 + r
//   log2e folded in (exp2 path).
// ---------------------------------------------------------------------------
__global__ __launch_bounds__(256) void biasprep_kernel(
    const float* __restrict__ z, const float* __restrict__ lnb_s,
    const float* __restrict__ lnb_b, const float* __restrict__ wb,
    const float* __restrict__ wq, const float* __restrict__ wk,
    const float* __restrict__ wv, const float* __restrict__ wg,
    const float* __restrict__ wo,
    float* __restrict__ bias32, unsigned short* __restrict__ wprep,
    unsigned short* __restrict__ wofrag)
{
    const int b = blockIdx.x;
    const int t = threadIdx.x;
    if (b < 256) {
        // ---- bias: block = one i, threads = j. Coalesced z stage via LDS. ----
        __shared__ float zL[256 * 33];               // pitch 33: conflict-free rows
        const float4* src = (const float4*)(z + (size_t)b * NJ * NC);
#pragma unroll
        for (int k = 0; k < 8; ++k) {
            int idx = t + 256 * k;                   // float4 index
            float4 v = src[idx];
            int f = idx * 4;
            int j = f >> 5, c = f & 31;
            zL[j * 33 + c]     = v.x; zL[j * 33 + c + 1] = v.y;
            zL[j * 33 + c + 2] = v.z; zL[j * 33 + c + 3] = v.w;
        }
        __syncthreads();

        float x[NC];
#pragma unroll
        for (int c = 0; c < NC; ++c) x[c] = zL[t * 33 + c];
        float mu = 0.f;
#pragma unroll
        for (int c = 0; c < NC; ++c) mu += x[c];
        mu *= (1.0f / NC);
        float var = 0.f;
#pragma unroll
        for (int c = 0; c < NC; ++c) { float d = x[c] - mu; var += d * d; }
        var *= (1.0f / NC);
        float rs = rsqrtf(var + LN_EPS);
        float acc[NH];
#pragma unroll
        for (int h = 0; h < NH; ++h) acc[h] = 0.f;
#pragma unroll
        for (int c = 0; c < NC; ++c) {
            float xn = (x[c] - mu) * rs * lnb_s[c] + lnb_b[c];
#pragma unroll
            for (int h = 0; h < NH; ++h) acc[h] += xn * wb[c * NH + h];
        }
        const int i = b;
        const int w_ = i >> 6, it = (i >> 4) & 3, lm = i & 15;
        const int jc = t >> 5, jt = (t >> 4) & 1, lq = (t >> 2) & 3, r = t & 3;
        const int base = jc * 8192 + w_ * 2048 + (jt * 4 + it) * 256
                       + (lq * 16 + lm) * 4 + r;
#pragma unroll
        for (int h = 0; h < NH; ++h)
            bias32[h * 65536 + base] = acc[h] * LOG2E;
    } else if (b < 272) {
        // ---- QKVG weight fragments ----
        int g = (b - 256) * 256 + t;                 // 0..4095
        int p  = g >> 10;
        int h  = (g >> 7) & 7;
        int ct = (g >> 6) & 1;
        int l  = g & 63;
        const float* W = (p == 0) ? wq : (p == 1) ? wk : (p == 2) ? wv : wg;
        float scale = (p == 0) ? QSCALE * LOG2E : (p == 3) ? LOG2E : 1.0f;
        int col = 32 * h + 16 * ct + (l & 15);
        int r0  = 8 * (l >> 4);
        float v[8];
#pragma unroll
        for (int e = 0; e < 8; ++e) v[e] = W[(r0 + e) * 256 + col] * scale;
        uint4 u;
        u.x = pk2c(v[0], v[1]); u.y = pk2c(v[2], v[3]);
        u.z = pk2c(v[4], v[5]); u.w = pk2c(v[6], v[7]);
        *(uint4*)&wprep[g * 8] = u;
    } else {
        // ---- wo B-fragments ----
        int g = (b - 272) * 256 + t;                 // 0..1023
        int tile = g >> 6;                           // kt*2+nt
        int l = g & 63;
        int kt = tile >> 1, nt = tile & 1;
        int r0 = kt * 32 + 8 * (l >> 4);
        int col = nt * 16 + (l & 15);
        float v[8];
#pragma unroll
        for (int e = 0; e < 8; ++e) v[e] = wo[(r0 + e) * 32 + col];
        uint4 u;
        u.x = pk2c(v[0], v[1]); u.y = pk2c(v[2], v[3]);
        u.z = pk2c(v[4], v[5]); u.w = pk2c(v[6], v[7]);
        *(uint4*)&wofrag[g * 8] = u;
    }
}

// ---------------------------------------------------------------------------
// Kernel 2: all-MFMA fused attention, 32 KB LDS -> up to 5 blocks/CU.
// KEY CHANGE vs prior: PV uses mfma_f32_16x16x16_bf16 in the O = P*V
// orientation. The QK^T D-layout (lane=i, regs=4 consecutive j) IS the
// K=16 A-frag layout, so P stays entirely in registers: the per-jc P
// LDS round-trip (8 ds_write + 4 ds_read_b128 + waits) is eliminated.
// V is stored pre-fragmented (K=16 B-frags) in VF; producer register
// layout == consumer fragment layout -> one conflict-free b64 read/tile.
// QPX buffer eliminated: X and Q^T stage through KX (wave-private rows,
// in-order DS pipe), K^T then overwrites. LDS: KX 16K | VF 16K = 32 KB.
// accO/gate orientation flips to lane=c, regs=i (consistent end-to-end).
// ---------------------------------------------------------------------------
__global__ __launch_bounds__(256, 4) void attn_kernel(
    const float* __restrict__ m, const float* __restrict__ ln_s,
    const float* __restrict__ ln_b,
    const unsigned short* __restrict__ wprep,
    const float* __restrict__ bias32,
    unsigned short* __restrict__ attn16)
{
    __shared__ unsigned short KX[256 * 32];   // X -> Q^T -> K rows (qkOff swizzle)
    __shared__ unsigned short VF[32 * 256];   // V K=16 B-frag tiles (J*2+ct)

    const int t = threadIdx.x;
    const int h = blockIdx.x & 7;
    const int s = blockIdx.x >> 3;
    const int l = t & 63, w = t >> 6;
    const int lm = l & 15, lq = l >> 4;
    const int ibase = w * 64;
    const floatx4 zero = {0.f, 0.f, 0.f, 0.f};

    // ---- Phase 1: LN(m[s][t]) -> KX row t (bf16, swizzled). Wave-private. ----
    {
        const float4* mr = (const float4*)(m + ((size_t)s * NI + t) * NC);
        float x[NC];
#pragma unroll
        for (int k = 0; k < 8; ++k) {
            float4 v = mr[k];
            x[4*k] = v.x; x[4*k+1] = v.y; x[4*k+2] = v.z; x[4*k+3] = v.w;
        }
        float mu = 0.f;
#pragma unroll
        for (int c = 0; c < NC; ++c) mu += x[c];
        mu *= (1.0f / NC);
        float var = 0.f;
#pragma unroll
        for (int c = 0; c < NC; ++c) { float d = x[c] - mu; var += d * d; }
        var *= (1.0f / NC);
        float rs = rsqrtf(var + LN_EPS);
#pragma unroll
        for (int k = 0; k < 4; ++k) {
            uint4 u;
            u.x = pk2c((x[8*k+0]-mu)*rs*ln_s[8*k+0]+ln_b[8*k+0],
                       (x[8*k+1]-mu)*rs*ln_s[8*k+1]+ln_b[8*k+1]);
            u.y = pk2c((x[8*k+2]-mu)*rs*ln_s[8*k+2]+ln_b[8*k+2],
                       (x[8*k+3]-mu)*rs*ln_s[8*k+3]+ln_b[8*k+3]);
            u.z = pk2c((x[8*k+4]-mu)*rs*ln_s[8*k+4]+ln_b[8*k+4],
                       (x[8*k+5]-mu)*rs*ln_s[8*k+5]+ln_b[8*k+5]);
            u.w = pk2c((x[8*k+6]-mu)*rs*ln_s[8*k+6]+ln_b[8*k+6],
                       (x[8*k+7]-mu)*rs*ln_s[8*k+7]+ln_b[8*k+7]);
            *(uint4*)&KX[qkOff(t, k)] = u;
        }
    }
    // no barrier: wave-private rows; DS pipe is in-order per wave

    // ---- Phase 2: MFMA projections. ----
    const unsigned short* wp = wprep + ((size_t)h * 128 + l) * 8;
    bf16x8 wfQ[2], wfK[2], wfV[2];
#pragma unroll
    for (int ct = 0; ct < 2; ++ct) {
        wfQ[ct] = *(const bf16x8*)&wp[(0 * 1024 + ct * 64) * 8];
        wfK[ct] = *(const bf16x8*)&wp[(1 * 1024 + ct * 64) * 8];
        wfV[ct] = *(const bf16x8*)&wp[(2 * 1024 + ct * 64) * 8];
    }
    bf16x8 Xb[4];                                 // retained for epilogue gate
#pragma unroll
    for (int it = 0; it < 4; ++it)
        Xb[it] = *(const bf16x8*)&KX[qkOff(ibase + it * 16 + lm, lq)];
    // KX (X) now dead for this wave -> reuse rows for Q^T

    // Q^T rows [i][c]  (D[c][i]: lane lm = i, regs = 4 consecutive c)
#pragma unroll
    for (int it = 0; it < 4; ++it)
#pragma unroll
        for (int ct = 0; ct < 2; ++ct) {
            floatx4 d = __builtin_amdgcn_mfma_f32_16x16x32_bf16(wfQ[ct], Xb[it], zero, 0, 0, 0);
            uint2 u; u.x = pk2c(d[0], d[1]); u.y = pk2c(d[2], d[3]);
            int row = ibase + it * 16 + lm;
            *(uint2*)&KX[qkOff(row, 2 * ct + (lq >> 1)) + (lq & 1) * 4] = u;
        }
    // Hoist own Q^T B-frags BEFORE K^T overwrites the same rows
    bf16x8 Qb[4];
#pragma unroll
    for (int it = 0; it < 4; ++it)
        Qb[it] = *(const bf16x8*)&KX[qkOff(ibase + it * 16 + lm, lq)];

    // K rows [j][c] -> KX (overwrite Q^T; own rows, in-order DS pipe)
#pragma unroll
    for (int it = 0; it < 4; ++it)
#pragma unroll
        for (int ct = 0; ct < 2; ++ct) {
            floatx4 d = __builtin_amdgcn_mfma_f32_16x16x32_bf16(wfK[ct], Xb[it], zero, 0, 0, 0);
            uint2 u; u.x = pk2c(d[0], d[1]); u.y = pk2c(d[2], d[3]);
            int row = ibase + it * 16 + lm;
            *(uint2*)&KX[qkOff(row, 2 * ct + (lq >> 1)) + (lq & 1) * 4] = u;
        }

    // V -> VF pre-fragmented K=16 B-frags.
    // Producer D (mfma(Xb[jt], wfV[ct])): lane lm = c', regs r = 4 consecutive j
    // == B-frag of 16x16x16 (lane lm = col c, elems e = k = 4*lq + e).
    // Tile id J = (j >> 4) = w*4 + jt; slot = (J*2+ct)*64 + l, 8B per lane.
#pragma unroll
    for (int jt = 0; jt < 4; ++jt)
#pragma unroll
        for (int ct = 0; ct < 2; ++ct) {
            floatx4 d = __builtin_amdgcn_mfma_f32_16x16x32_bf16(Xb[jt], wfV[ct], zero, 0, 0, 0);
            uint2 u; u.x = pk2c(d[0], d[1]); u.y = pk2c(d[2], d[3]);
            int tile = (w * 4 + jt) * 2 + ct;
            *(uint2*)&VF[(tile * 64 + l) * 4] = u;
        }

    __syncthreads();   // KX (K) / VF visible to all waves (the only barrier)

    floatx4 accO[2][4];
#pragma unroll
    for (int ct = 0; ct < 2; ++ct)
#pragma unroll
        for (int it = 0; it < 4; ++it) accO[ct][it] = zero;
    floatx4 accL[4];                // denominator via ones-B MFMA (K=16)
#pragma unroll
    for (int it = 0; it < 4; ++it) accL[it] = zero;
    short4v onesB;
#pragma unroll
    for (int e = 0; e < 4; ++e) onesB[e] = (short)0x3F80;   // bf16 1.0

    const float* bptr = bias32 + (size_t)h * 65536 + w * 2048 + l * 4;

    // ---- Phase 3: j-loop, 32 j per iteration; P entirely in registers ----
    for (int jc = 0; jc < 8; ++jc) {
        const float* bj = bptr + jc * 8192;
#pragma unroll
        for (int jt = 0; jt < 2; ++jt) {
            bf16x8 Ka = *(const bf16x8*)&KX[qkOff(jc * 32 + jt * 16 + lm, lq)];
            const int J = jc * 2 + jt;
            short4v Vb0 = *(const short4v*)&VF[((J * 2 + 0) * 64 + l) * 4];
            short4v Vb1 = *(const short4v*)&VF[((J * 2 + 1) * 64 + l) * 4];
#pragma unroll
            for (int it = 0; it < 4; ++it) {
                floatx4 C = *(const floatx4*)(bj + (jt * 4 + it) * 256);
                floatx4 S = __builtin_amdgcn_mfma_f32_16x16x32_bf16(Ka, Qb[it], C, 0, 0, 0);
                // S: lane lm = i, regs r = j = 16*jt + 4*lq + r
                // == A-frag of 16x16x16 (row m = i = lm, k = 4*lq + e)
                union { unsigned u[2]; short4v s4; } pu;
                pu.u[0] = pkbb((__bf16)fexp2(S[0]), (__bf16)fexp2(S[1]));
                pu.u[1] = pkbb((__bf16)fexp2(S[2]), (__bf16)fexp2(S[3]));
                accO[0][it] = __builtin_amdgcn_mfma_f32_16x16x16bf16_1k(pu.s4, Vb0, accO[0][it], 0, 0, 0);
                accO[1][it] = __builtin_amdgcn_mfma_f32_16x16x16bf16_1k(pu.s4, Vb1, accO[1][it], 0, 0, 0);
                accL[it]    = __builtin_amdgcn_mfma_f32_16x16x16bf16_1k(pu.s4, onesB, accL[it], 0, 0, 0);
            }
        }
    }

    // ---- Epilogue: gate (lane=c, regs=i orientation), normalize, store ----
    // G = mfma(Xb as A, wfG as B): D col lm = c_out, row (4*lq+r) = i  --
    // matches accO/accL (accL reg r = L[i = it*16 + 4*lq + r]).
    {
        bf16x8 wfG0 = *(const bf16x8*)&wp[(3 * 1024 + 0 * 64) * 8];
        bf16x8 wfG1 = *(const bf16x8*)&wp[(3 * 1024 + 1 * 64) * 8];
        __bf16* a16 = (__bf16*)attn16;
#pragma unroll
        for (int it = 0; it < 4; ++it) {
            floatx4 g0 = __builtin_amdgcn_mfma_f32_16x16x32_bf16(Xb[it], wfG0, zero, 0, 0, 0);
            floatx4 g1 = __builtin_amdgcn_mfma_f32_16x16x32_bf16(Xb[it], wfG1, zero, 0, 0, 0);
#pragma unroll
            for (int r = 0; r < 4; ++r) {
                const float inv = frcp(accL[it][r]);
                float o0 = accO[0][it][r] * inv * frcp(1.0f + fexp2(-g0[r]));
                float o1 = accO[1][it][r] * inv * frcp(1.0f + fexp2(-g1[r]));
                const size_t rowb = ((size_t)s * NI + ibase + it * 16 + lq * 4 + r) * 256 + h * 32;
                a16[rowb + lm]      = (__bf16)o0;
                a16[rowb + 16 + lm] = (__bf16)o1;
            }
        }
    }
}

// ---------------------------------------------------------------------------
// Kernel 3: MFMA output projection. out = attn16(32768x256) @ wo(256x32) + bo
// ---------------------------------------------------------------------------
__global__ __launch_bounds__(256) void proj_kernel(
    const unsigned short* __restrict__ attn16,
    const unsigned short* __restrict__ wofrag,
    const float* __restrict__ bo, float* __restrict__ out)
{
    const int t = threadIdx.x;
    const int l = t & 63, w = t >> 6;
    const int lm = l & 15, lq = l >> 4;
    const int row0 = blockIdx.x * 128 + w * 32;
    const floatx4 zero = {0.f, 0.f, 0.f, 0.f};

    floatx4 acc[2][2];
#pragma unroll
    for (int it = 0; it < 2; ++it)
#pragma unroll
        for (int nt = 0; nt < 2; ++nt) acc[it][nt] = zero;

#pragma unroll 2
    for (int kt = 0; kt < 8; ++kt) {
        bf16x8 a0 = *(const bf16x8*)&attn16[(size_t)(row0 + lm) * 256 + kt * 32 + lq * 8];
        bf16x8 a1 = *(const bf16x8*)&attn16[(size_t)(row0 + 16 + lm) * 256 + kt * 32 + lq * 8];
        bf16x8 b0 = *(const bf16x8*)&wofrag[((kt * 2 + 0) * 64 + l) * 8];
        bf16x8 b1 = *(const bf16x8*)&wofrag[((kt * 2 + 1) * 64 + l) * 8];
        acc[0][0] = __builtin_amdgcn_mfma_f32_16x16x32_bf16(a0, b0, acc[0][0], 0, 0, 0);
        acc[0][1] = __builtin_amdgcn_mfma_f32_16x16x32_bf16(a0, b1, acc[0][1], 0, 0, 0);
        acc[1][0] = __builtin_amdgcn_mfma_f32_16x16x32_bf16(a1, b0, acc[1][0], 0, 0, 0);
        acc[1][1] = __builtin_amdgcn_mfma_f32_16x16x32_bf16(a1, b1, acc[1][1], 0, 0, 0);
    }

    float bov[2] = {bo[lm], bo[16 + lm]};
#pragma unroll
    for (int it = 0; it < 2; ++it)
#pragma unroll
        for (int nt = 0; nt < 2; ++nt)
#pragma unroll
            for (int r = 0; r < 4; ++r)
                out[(size_t)(row0 + it * 16 + lq * 4 + r) * NC + nt * 16 + lm]
                    = acc[it][nt][r] + bov[nt];
}

// ---------------------------------------------------------------------------
extern "C" void kernel_launch(void* const* d_in, const int* in_sizes, int n_in,
                              void* d_out, int out_size, void* d_ws, size_t ws_size,
                              hipStream_t stream) {
    const float* m     = (const float*)d_in[0];
    const float* z     = (const float*)d_in[1];
    const float* ln_s  = (const float*)d_in[2];
    const float* ln_b  = (const float*)d_in[3];
    const float* lnb_s = (const float*)d_in[4];
    const float* lnb_b = (const float*)d_in[5];
    const float* wq    = (const float*)d_in[6];
    const float* wk    = (const float*)d_in[7];
    const float* wv    = (const float*)d_in[8];
    const float* wb    = (const float*)d_in[9];
    const float* wg    = (const float*)d_in[10];
    const float* wo    = (const float*)d_in[11];
    const float* bo    = (const float*)d_in[12];
    float* out = (float*)d_out;

    // ws: bias32 2 MB | wprep 64 KB | wofrag 16 KB | attn16 16.78 MB
    float* bias32 = (float*)d_ws;
    unsigned short* wprep  = (unsigned short*)((char*)d_ws + (2u << 20));
    unsigned short* wofrag = (unsigned short*)((char*)d_ws + (2u << 20) + 65536);
    unsigned short* attn16 = (unsigned short*)((char*)d_ws + (2u << 20) + 65536 + 16384);

    biasprep_kernel<<<276, 256, 0, stream>>>(z, lnb_s, lnb_b, wb, wq, wk, wv, wg,
                                             wo, bias32, wprep, wofrag);
    attn_kernel<<<NS * NH, 256, 0, stream>>>(m, ln_s, ln_b, wprep, bias32, attn16);
    proj_kernel<<<(NS * NI) / 128, 256, 0, stream>>>(attn16, wofrag, bo, out);
}

// Round 3
// 123.603 us; speedup vs baseline: 1.0543x; 1.0376x over previous
//
#include <hip/hip_runtime.h>

constexpr int NC = 32;    // channels C
constexpr int NH = 8;     // heads
constexpr int NS = 128;   // s
constexpr int NI = 256;   // i (q rows)
constexpr int NJ = 256;   // j (kv rows)
constexpr float LN_EPS = 1e-5f;
constexpr float QSCALE = 0.17677669529663687f;   // C^-0.5
constexpr float LOG2E  = 1.4426950408889634f;

typedef __bf16 bf16x8 __attribute__((ext_vector_type(8)));
typedef __bf16 bf16x2 __attribute__((ext_vector_type(2)));
typedef float floatx4 __attribute__((ext_vector_type(4)));

__device__ __forceinline__ float fexp2(float x) {
#if __has_builtin(__builtin_amdgcn_exp2f)
    return __builtin_amdgcn_exp2f(x);
#else
    return exp2f(x);
#endif
}
__device__ __forceinline__ float frcp(float x) {
#if __has_builtin(__builtin_amdgcn_rcpf)
    return __builtin_amdgcn_rcpf(x);
#else
    return 1.0f / x;
#endif
}
// HW bf16 pack (v_cvt_pk_bf16_f32 on gfx950), RNE
__device__ __forceinline__ unsigned pk2c(float a, float b) {
    union { bf16x2 v; unsigned u; } c;
    c.v = bf16x2{(__bf16)a, (__bf16)b};
    return c.u;
}

// XOR-swizzled LDS offsets (shorts). Rows of 32 shorts (4 x 16B chunks):
// phys_chunk = chunk ^ ((row>>1)&3)  -> <=2-way banks on all b128 reads.
__device__ __forceinline__ int qkOff(int row, int chunk) {
    return row * 32 + ((chunk ^ ((row >> 1) & 3)) << 3);
}
// V^T rows of 256 shorts (32 chunks): phys_chunk = chunk ^ (c&7).
__device__ __forceinline__ int vOff(int c, int chunk) {
    return c * 256 + ((chunk ^ (c & 7)) << 3);
}
// Per-wave P slab (16 rows x 32 shorts), same swizzle family as qkOff.
__device__ __forceinline__ int pOff(int wbase, int row, int chunk) {
    return wbase + row * 32 + ((chunk ^ ((row >> 1) & 3)) << 3);
}

// ---------------------------------------------------------------------------
// Kernel 1 (merged): blocks 0..255   : pair bias -> fp32 MFMA-C-fragment layout
//                    blocks 256..271 : wq/wk/wv/wg fragment prep (bf16)
//                    blocks 272..275 : wo B-fragment prep (bf16)
// bias32 layout: off(h,i,j) = h*65536 + jc*8192 + w*2048 + (jt*4+it)*256 + l*4 + r
//   log2e folded in (exp2 path).
// ---------------------------------------------------------------------------
__global__ __launch_bounds__(256) void biasprep_kernel(
    const float* __restrict__ z, const float* __restrict__ lnb_s,
    const float* __restrict__ lnb_b, const float* __restrict__ wb,
    const float* __restrict__ wq, const float* __restrict__ wk,
    const float* __restrict__ wv, const float* __restrict__ wg,
    const float* __restrict__ wo,
    float* __restrict__ bias32, unsigned short* __restrict__ wprep,
    unsigned short* __restrict__ wofrag)
{
    const int b = blockIdx.x;
    const int t = threadIdx.x;
    if (b < 256) {
        // ---- bias: block = one i, threads = j. Coalesced z stage via LDS. ----
        __shared__ float zL[256 * 33];               // pitch 33: conflict-free rows
        const float4* src = (const float4*)(z + (size_t)b * NJ * NC);
#pragma unroll
        for (int k = 0; k < 8; ++k) {
            int idx = t + 256 * k;                   // float4 index
            float4 v = src[idx];
            int f = idx * 4;
            int j = f >> 5, c = f & 31;
            zL[j * 33 + c]     = v.x; zL[j * 33 + c + 1] = v.y;
            zL[j * 33 + c + 2] = v.z; zL[j * 33 + c + 3] = v.w;
        }
        __syncthreads();

        float x[NC];
#pragma unroll
        for (int c = 0; c < NC; ++c) x[c] = zL[t * 33 + c];
        float mu = 0.f;
#pragma unroll
        for (int c = 0; c < NC; ++c) mu += x[c];
        mu *= (1.0f / NC);
        float var = 0.f;
#pragma unroll
        for (int c = 0; c < NC; ++c) { float d = x[c] - mu; var += d * d; }
        var *= (1.0f / NC);
        float rs = rsqrtf(var + LN_EPS);
        float acc[NH];
#pragma unroll
        for (int h = 0; h < NH; ++h) acc[h] = 0.f;
#pragma unroll
        for (int c = 0; c < NC; ++c) {
            float xn = (x[c] - mu) * rs * lnb_s[c] + lnb_b[c];
#pragma unroll
            for (int h = 0; h < NH; ++h) acc[h] += xn * wb[c * NH + h];
        }
        const int i = b;
        const int w_ = i >> 6, it = (i >> 4) & 3, lm = i & 15;
        const int jc = t >> 5, jt = (t >> 4) & 1, lq = (t >> 2) & 3, r = t & 3;
        const int base = jc * 8192 + w_ * 2048 + (jt * 4 + it) * 256
                       + (lq * 16 + lm) * 4 + r;
#pragma unroll
        for (int h = 0; h < NH; ++h)
            bias32[h * 65536 + base] = acc[h] * LOG2E;
    } else if (b < 272) {
        // ---- QKVG weight fragments ----
        int g = (b - 256) * 256 + t;                 // 0..4095
        int p  = g >> 10;
        int h  = (g >> 7) & 7;
        int ct = (g >> 6) & 1;
        int l  = g & 63;
        const float* W = (p == 0) ? wq : (p == 1) ? wk : (p == 2) ? wv : wg;
        float scale = (p == 0) ? QSCALE * LOG2E : (p == 3) ? LOG2E : 1.0f;
        int col = 32 * h + 16 * ct + (l & 15);
        int r0  = 8 * (l >> 4);
        float v[8];
#pragma unroll
        for (int e = 0; e < 8; ++e) v[e] = W[(r0 + e) * 256 + col] * scale;
        uint4 u;
        u.x = pk2c(v[0], v[1]); u.y = pk2c(v[2], v[3]);
        u.z = pk2c(v[4], v[5]); u.w = pk2c(v[6], v[7]);
        *(uint4*)&wprep[g * 8] = u;
    } else {
        // ---- wo B-fragments ----
        int g = (b - 272) * 256 + t;                 // 0..1023
        int tile = g >> 6;                           // kt*2+nt
        int l = g & 63;
        int kt = tile >> 1, nt = tile & 1;
        int r0 = kt * 32 + 8 * (l >> 4);
        int col = nt * 16 + (l & 15);
        float v[8];
#pragma unroll
        for (int e = 0; e < 8; ++e) v[e] = wo[(r0 + e) * 32 + col];
        uint4 u;
        u.x = pk2c(v[0], v[1]); u.y = pk2c(v[2], v[3]);
        u.z = pk2c(v[4], v[5]); u.w = pk2c(v[6], v[7]);
        *(uint4*)&wofrag[g * 8] = u;
    }
}

// ---------------------------------------------------------------------------
// Kernel 2: all-MFMA fused attention. 36 KB LDS -> 4 blocks/CU (16 waves),
// exact residency (1024 = 256 CU x 4, no tail).
// j-loop = 16 K32 MFMA issues/jc (QK 8 + PV 8): denominator moved OFF the
// MFMA pipe (VALU adds on the in-register f32 exp2 results, lane = i, then
// shfl_xor reduce over lq at epilogue). P transposed through a 1 KB/wave
// slab (write 2x b64, read 1x b128 per (it,jc)) -- wave-private, in-order
// DS pipe, no barriers in the loop.
// LDS: KX (X -> Q^T -> K) 16K | Vt (V^T [c][j]) 16K | Pbuf 4K = 36 KB.
// ---------------------------------------------------------------------------
__global__ __launch_bounds__(256, 4) void attn_kernel(
    const float* __restrict__ m, const float* __restrict__ ln_s,
    const float* __restrict__ ln_b,
    const unsigned short* __restrict__ wprep,
    const float* __restrict__ bias32,
    unsigned short* __restrict__ attn16)
{
    __shared__ unsigned short KX[256 * 32];   // X -> Q^T -> K rows (qkOff swizzle)
    __shared__ unsigned short Vt[32 * 256];   // V^T [c][j] (vOff swizzle)
    __shared__ unsigned short Pbuf[4 * 512];  // per-wave P slab (16 x 32)

    const int t = threadIdx.x;
    const int h = blockIdx.x & 7;
    const int s = blockIdx.x >> 3;
    const int l = t & 63, w = t >> 6;
    const int lm = l & 15, lq = l >> 4;
    const int ibase = w * 64;
    const int pwb = w * 512;
    const floatx4 zero = {0.f, 0.f, 0.f, 0.f};

    // ---- Phase 1: LN(m[s][t]) -> KX row t (bf16, swizzled). Wave-private. ----
    {
        const float4* mr = (const float4*)(m + ((size_t)s * NI + t) * NC);
        float x[NC];
#pragma unroll
        for (int k = 0; k < 8; ++k) {
            float4 v = mr[k];
            x[4*k] = v.x; x[4*k+1] = v.y; x[4*k+2] = v.z; x[4*k+3] = v.w;
        }
        float mu = 0.f;
#pragma unroll
        for (int c = 0; c < NC; ++c) mu += x[c];
        mu *= (1.0f / NC);
        float var = 0.f;
#pragma unroll
        for (int c = 0; c < NC; ++c) { float d = x[c] - mu; var += d * d; }
        var *= (1.0f / NC);
        float rs = rsqrtf(var + LN_EPS);
#pragma unroll
        for (int k = 0; k < 4; ++k) {
            uint4 u;
            u.x = pk2c((x[8*k+0]-mu)*rs*ln_s[8*k+0]+ln_b[8*k+0],
                       (x[8*k+1]-mu)*rs*ln_s[8*k+1]+ln_b[8*k+1]);
            u.y = pk2c((x[8*k+2]-mu)*rs*ln_s[8*k+2]+ln_b[8*k+2],
                       (x[8*k+3]-mu)*rs*ln_s[8*k+3]+ln_b[8*k+3]);
            u.z = pk2c((x[8*k+4]-mu)*rs*ln_s[8*k+4]+ln_b[8*k+4],
                       (x[8*k+5]-mu)*rs*ln_s[8*k+5]+ln_b[8*k+5]);
            u.w = pk2c((x[8*k+6]-mu)*rs*ln_s[8*k+6]+ln_b[8*k+6],
                       (x[8*k+7]-mu)*rs*ln_s[8*k+7]+ln_b[8*k+7]);
            *(uint4*)&KX[qkOff(t, k)] = u;
        }
    }
    // no barrier: wave-private rows; DS pipe is in-order per wave

    // ---- Phase 2: MFMA projections. Gate deferred to epilogue. ----
    const unsigned short* wp = wprep + ((size_t)h * 128 + l) * 8;
    bf16x8 wfQ[2], wfK[2], wfV[2];
#pragma unroll
    for (int ct = 0; ct < 2; ++ct) {
        wfQ[ct] = *(const bf16x8*)&wp[(0 * 1024 + ct * 64) * 8];
        wfK[ct] = *(const bf16x8*)&wp[(1 * 1024 + ct * 64) * 8];
        wfV[ct] = *(const bf16x8*)&wp[(2 * 1024 + ct * 64) * 8];
    }
    bf16x8 Xb[4];                                 // retained for epilogue gate
#pragma unroll
    for (int it = 0; it < 4; ++it)
        Xb[it] = *(const bf16x8*)&KX[qkOff(ibase + it * 16 + lm, lq)];
    // KX (X) now dead for this wave -> reuse rows for Q^T

    // Q^T rows [i][c]  (D[c][i]: lane lm = i, regs = 4 consecutive c)
#pragma unroll
    for (int it = 0; it < 4; ++it)
#pragma unroll
        for (int ct = 0; ct < 2; ++ct) {
            floatx4 d = __builtin_amdgcn_mfma_f32_16x16x32_bf16(wfQ[ct], Xb[it], zero, 0, 0, 0);
            uint2 u; u.x = pk2c(d[0], d[1]); u.y = pk2c(d[2], d[3]);
            int row = ibase + it * 16 + lm;
            *(uint2*)&KX[qkOff(row, 2 * ct + (lq >> 1)) + (lq & 1) * 4] = u;
        }
    // Hoist own Q^T B-frags BEFORE K overwrites the same rows
    bf16x8 Qb[4];
#pragma unroll
    for (int it = 0; it < 4; ++it)
        Qb[it] = *(const bf16x8*)&KX[qkOff(ibase + it * 16 + lm, lq)];

    // K rows [j][c] -> KX (overwrite Q^T; own rows, in-order DS pipe)
#pragma unroll
    for (int it = 0; it < 4; ++it)
#pragma unroll
        for (int ct = 0; ct < 2; ++ct) {
            floatx4 d = __builtin_amdgcn_mfma_f32_16x16x32_bf16(wfK[ct], Xb[it], zero, 0, 0, 0);
            uint2 u; u.x = pk2c(d[0], d[1]); u.y = pk2c(d[2], d[3]);
            int row = ibase + it * 16 + lm;
            *(uint2*)&KX[qkOff(row, 2 * ct + (lq >> 1)) + (lq & 1) * 4] = u;
        }

    // V -> Vt [c][j]  (D[j][c']: lane lm = c', regs = 4 consecutive j)
#pragma unroll
    for (int jt = 0; jt < 4; ++jt)
#pragma unroll
        for (int ct = 0; ct < 2; ++ct) {
            floatx4 d = __builtin_amdgcn_mfma_f32_16x16x32_bf16(Xb[jt], wfV[ct], zero, 0, 0, 0);
            uint2 u; u.x = pk2c(d[0], d[1]); u.y = pk2c(d[2], d[3]);
            int c = ct * 16 + lm;
            int chunk = 8 * w + 2 * jt + (lq >> 1);
            *(uint2*)&Vt[vOff(c, chunk) + (lq & 1) * 4] = u;
        }

    __syncthreads();   // KX (K) / Vt visible to all waves (the only barrier)

    floatx4 accO[2][4];
#pragma unroll
    for (int ct = 0; ct < 2; ++ct)
#pragma unroll
        for (int it = 0; it < 4; ++it) accO[ct][it] = zero;
    float accLv[4] = {0.f, 0.f, 0.f, 0.f};        // denominator, VALU (lane = i)

    const float* bptr = bias32 + (size_t)h * 65536 + w * 2048 + l * 4;

    // ---- Phase 3: j-loop, 32 j per iteration; 16 K32 MFMA issues ----
    for (int jc = 0; jc < 8; ++jc) {
        const float* bj = bptr + jc * 8192;
        bf16x8 Ka0 = *(const bf16x8*)&KX[qkOff(jc * 32 + lm, lq)];
        bf16x8 Ka1 = *(const bf16x8*)&KX[qkOff(jc * 32 + 16 + lm, lq)];
        bf16x8 Va0 = *(const bf16x8*)&Vt[vOff(lm, 4 * jc + lq)];
        bf16x8 Va1 = *(const bf16x8*)&Vt[vOff(16 + lm, 4 * jc + lq)];
#pragma unroll
        for (int it = 0; it < 4; ++it) {
            floatx4 C0 = *(const floatx4*)(bj + it * 256);
            floatx4 S0 = __builtin_amdgcn_mfma_f32_16x16x32_bf16(Ka0, Qb[it], C0, 0, 0, 0);
            floatx4 C1 = *(const floatx4*)(bj + (4 + it) * 256);
            floatx4 S1 = __builtin_amdgcn_mfma_f32_16x16x32_bf16(Ka1, Qb[it], C1, 0, 0, 0);
            float p0 = fexp2(S0[0]), p1 = fexp2(S0[1]);
            float p2 = fexp2(S0[2]), p3 = fexp2(S0[3]);
            float p4 = fexp2(S1[0]), p5 = fexp2(S1[1]);
            float p6 = fexp2(S1[2]), p7 = fexp2(S1[3]);
            accLv[it] += ((p0 + p1) + (p2 + p3)) + ((p4 + p5) + (p6 + p7));
            uint2 u0; u0.x = pk2c(p0, p1); u0.y = pk2c(p2, p3);
            uint2 u1; u1.x = pk2c(p4, p5); u1.y = pk2c(p6, p7);
            // j = 16*jt + 4*lq + r -> chunk = 2*jt + (lq>>1), off (lq&1)*4
            *(uint2*)&Pbuf[pOff(pwb, lm, 0 + (lq >> 1)) + (lq & 1) * 4] = u0;
            *(uint2*)&Pbuf[pOff(pwb, lm, 2 + (lq >> 1)) + (lq & 1) * 4] = u1;
            bf16x8 Pb = *(const bf16x8*)&Pbuf[pOff(pwb, lm, lq)];
            accO[0][it] = __builtin_amdgcn_mfma_f32_16x16x32_bf16(Va0, Pb, accO[0][it], 0, 0, 0);
            accO[1][it] = __builtin_amdgcn_mfma_f32_16x16x32_bf16(Va1, Pb, accO[1][it], 0, 0, 0);
        }
    }

    // ---- Epilogue: reduce L over lq, gate from retained Xb, store ----
    // accO / gate orientation: lane lm = i, regs = c' (4*lq + r per ct).
    {
        bf16x8 wfG0 = *(const bf16x8*)&wp[(3 * 1024 + 0 * 64) * 8];
        bf16x8 wfG1 = *(const bf16x8*)&wp[(3 * 1024 + 1 * 64) * 8];
#pragma unroll
        for (int it = 0; it < 4; ++it) {
            float L = accLv[it];
            L += __shfl_xor(L, 16, 64);
            L += __shfl_xor(L, 32, 64);
            const float inv = frcp(L);               // L[i = ibase + it*16 + lm]
            floatx4 d0 = __builtin_amdgcn_mfma_f32_16x16x32_bf16(wfG0, Xb[it], zero, 0, 0, 0);
            floatx4 d1 = __builtin_amdgcn_mfma_f32_16x16x32_bf16(wfG1, Xb[it], zero, 0, 0, 0);
            const size_t rowb = ((size_t)s * NI + ibase + it * 16 + lm) * 256 + h * 32;
            {
                float o0 = accO[0][it][0] * inv * frcp(1.0f + fexp2(-d0[0]));
                float o1 = accO[0][it][1] * inv * frcp(1.0f + fexp2(-d0[1]));
                float o2 = accO[0][it][2] * inv * frcp(1.0f + fexp2(-d0[2]));
                float o3 = accO[0][it][3] * inv * frcp(1.0f + fexp2(-d0[3]));
                uint2 u; u.x = pk2c(o0, o1); u.y = pk2c(o2, o3);
                *(uint2*)&attn16[rowb + 0 * 16 + lq * 4] = u;
            }
            {
                float o0 = accO[1][it][0] * inv * frcp(1.0f + fexp2(-d1[0]));
                float o1 = accO[1][it][1] * inv * frcp(1.0f + fexp2(-d1[1]));
                float o2 = accO[1][it][2] * inv * frcp(1.0f + fexp2(-d1[2]));
                float o3 = accO[1][it][3] * inv * frcp(1.0f + fexp2(-d1[3]));
                uint2 u; u.x = pk2c(o0, o1); u.y = pk2c(o2, o3);
                *(uint2*)&attn16[rowb + 1 * 16 + lq * 4] = u;
            }
        }
    }
}

// ---------------------------------------------------------------------------
// Kernel 3: MFMA output projection. out = attn16(32768x256) @ wo(256x32) + bo
// ---------------------------------------------------------------------------
__global__ __launch_bounds__(256) void proj_kernel(
    const unsigned short* __restrict__ attn16,
    const unsigned short* __restrict__ wofrag,
    const float* __restrict__ bo, float* __restrict__ out)
{
    const int t = threadIdx.x;
    const int l = t & 63, w = t >> 6;
    const int lm = l & 15, lq = l >> 4;
    const int row0 = blockIdx.x * 128 + w * 32;
    const floatx4 zero = {0.f, 0.f, 0.f, 0.f};

    floatx4 acc[2][2];
#pragma unroll
    for (int it = 0; it < 2; ++it)
#pragma unroll
        for (int nt = 0; nt < 2; ++nt) acc[it][nt] = zero;

#pragma unroll 2
    for (int kt = 0; kt < 8; ++kt) {
        bf16x8 a0 = *(const bf16x8*)&attn16[(size_t)(row0 + lm) * 256 + kt * 32 + lq * 8];
        bf16x8 a1 = *(const bf16x8*)&attn16[(size_t)(row0 + 16 + lm) * 256 + kt * 32 + lq * 8];
        bf16x8 b0 = *(const bf16x8*)&wofrag[((kt * 2 + 0) * 64 + l) * 8];
        bf16x8 b1 = *(const bf16x8*)&wofrag[((kt * 2 + 1) * 64 + l) * 8];
        acc[0][0] = __builtin_amdgcn_mfma_f32_16x16x32_bf16(a0, b0, acc[0][0], 0, 0, 0);
        acc[0][1] = __builtin_amdgcn_mfma_f32_16x16x32_bf16(a0, b1, acc[0][1], 0, 0, 0);
        acc[1][0] = __builtin_amdgcn_mfma_f32_16x16x32_bf16(a1, b0, acc[1][0], 0, 0, 0);
        acc[1][1] = __builtin_amdgcn_mfma_f32_16x16x32_bf16(a1, b1, acc[1][1], 0, 0, 0);
    }

    float bov[2] = {bo[lm], bo[16 + lm]};
#pragma unroll
    for (int it = 0; it < 2; ++it)
#pragma unroll
        for (int nt = 0; nt < 2; ++nt)
#pragma unroll
            for (int r = 0; r < 4; ++r)
                out[(size_t)(row0 + it * 16 + lq * 4 + r) * NC + nt * 16 + lm]
                    = acc[it][nt][r] + bov[nt];
}

// ---------------------------------------------------------------------------
extern "C" void kernel_launch(void* const* d_in, const int* in_sizes, int n_in,
                              void* d_out, int out_size, void* d_ws, size_t ws_size,
                              hipStream_t stream) {
    const float* m     = (const float*)d_in[0];
    const float* z     = (const float*)d_in[1];
    const float* ln_s  = (const float*)d_in[2];
    const float* ln_b  = (const float*)d_in[3];
    const float* lnb_s = (const float*)d_in[4];
    const float* lnb_b = (const float*)d_in[5];
    const float* wq    = (const float*)d_in[6];
    const float* wk    = (const float*)d_in[7];
    const float* wv    = (const float*)d_in[8];
    const float* wb    = (const float*)d_in[9];
    const float* wg    = (const float*)d_in[10];
    const float* wo    = (const float*)d_in[11];
    const float* bo    = (const float*)d_in[12];
    float* out = (float*)d_out;

    // ws: bias32 2 MB | wprep 64 KB | wofrag 16 KB | attn16 16.78 MB
    float* bias32 = (float*)d_ws;
    unsigned short* wprep  = (unsigned short*)((char*)d_ws + (2u << 20));
    unsigned short* wofrag = (unsigned short*)((char*)d_ws + (2u << 20) + 65536);
    unsigned short* attn16 = (unsigned short*)((char*)d_ws + (2u << 20) + 65536 + 16384);

    biasprep_kernel<<<276, 256, 0, stream>>>(z, lnb_s, lnb_b, wb, wq, wk, wv, wg,
                                             wo, bias32, wprep, wofrag);
    attn_kernel<<<NS * NH, 256, 0, stream>>>(m, ln_s, ln_b, wprep, bias32, attn16);
    proj_kernel<<<(NS * NI) / 128, 256, 0, stream>>>(attn16, wofrag, bo, out);
}